// Round 8
// baseline (73.558 us; speedup 1.0000x reference)
//
#include <hip/hip_runtime.h>

#define NQ 8
#define NLAYERS 3

typedef unsigned int uint2ev __attribute__((ext_vector_type(2)));

// ---- cross-lane xor exchange, zero DS ops for all masks ----
template<int MASK>
__device__ __forceinline__ float xorlane(float v, int lane) {
    if constexpr (MASK == 1) {
        return __int_as_float(__builtin_amdgcn_mov_dpp(__float_as_int(v), 0xB1, 0xF, 0xF, false)); // quad_perm [1,0,3,2]
    } else if constexpr (MASK == 2) {
        return __int_as_float(__builtin_amdgcn_mov_dpp(__float_as_int(v), 0x4E, 0xF, 0xF, false)); // quad_perm [2,3,0,1]
    } else if constexpr (MASK == 4) {
        float a = __int_as_float(__builtin_amdgcn_update_dpp(0, __float_as_int(v), 0x114, 0xF, 0xF, false)); // row_shr:4
        float b = __int_as_float(__builtin_amdgcn_update_dpp(0, __float_as_int(v), 0x104, 0xF, 0xF, false)); // row_shl:4
        return (lane & 4) ? a : b;
    } else if constexpr (MASK == 8) {
        return __int_as_float(__builtin_amdgcn_mov_dpp(__float_as_int(v), 0x128, 0xF, 0xF, false)); // row_ror:8 == xor 8
    }
#if __has_builtin(__builtin_amdgcn_permlane16_swap)
    else if constexpr (MASK == 16) {
        uint2ev r = __builtin_amdgcn_permlane16_swap(__float_as_uint(v), __float_as_uint(v), false, false);
        return __uint_as_float((lane & 16) ? r.x : r.y);
    }
#endif
#if __has_builtin(__builtin_amdgcn_permlane32_swap)
    else if constexpr (MASK == 32) {
        uint2ev r = __builtin_amdgcn_permlane32_swap(__float_as_uint(v), __float_as_uint(v), false, false);
        return __uint_as_float((lane & 32) ? r.x : r.y);
    }
#endif
    else {
        return __shfl_xor(v, MASK);
    }
}

// ---- DPP-fused wave64 sum; total lands in lane 63, zero DS ops ----
template<int CTRL>
__device__ __forceinline__ float dpp_add_stage(float v) {
    int moved = __builtin_amdgcn_update_dpp(0, __float_as_int(v), CTRL, 0xF, 0xF, false);
    return v + __int_as_float(moved);
}
__device__ __forceinline__ float wave_sum63(float v) {
    v = dpp_add_stage<0x111>(v);   // row_shr:1
    v = dpp_add_stage<0x112>(v);   // row_shr:2
    v = dpp_add_stage<0x114>(v);   // row_shr:4
    v = dpp_add_stage<0x118>(v);   // row_shr:8
    v = dpp_add_stage<0x142>(v);   // row_bcast:15
    v = dpp_add_stage<0x143>(v);   // row_bcast:31
    return v;                      // lane 63 has the full sum
}

__device__ __forceinline__ void ry_pair(float c, float s, float& a0, float& a1) {
    float n0 = c * a0 - s * a1;
    float n1 = s * a0 + c * a1;
    a0 = n0; a1 = n1;
}

template<int Q>
__device__ __forceinline__ void apply_ry_t(float c, float s, float ar[4], float ai[4], int lane) {
    if constexpr (Q == 0) {
        ry_pair(c, s, ar[0], ar[1]); ry_pair(c, s, ai[0], ai[1]);
        ry_pair(c, s, ar[2], ar[3]); ry_pair(c, s, ai[2], ai[3]);
    } else if constexpr (Q == 1) {
        ry_pair(c, s, ar[0], ar[2]); ry_pair(c, s, ai[0], ai[2]);
        ry_pair(c, s, ar[1], ar[3]); ry_pair(c, s, ai[1], ai[3]);
    } else {
        constexpr int mask = 1 << (Q - 2);
        float sgn = (lane & mask) ? s : -s;
#pragma unroll
        for (int j = 0; j < 4; ++j) {
            float pr = xorlane<mask>(ar[j], lane);
            float pq = xorlane<mask>(ai[j], lane);
            ar[j] = c * ar[j] + sgn * pr;
            ai[j] = c * ai[j] + sgn * pq;
        }
    }
}

__device__ __forceinline__ void rz_amp(float cp, float ssp, float& r, float& i) {
    float nr = r * cp - i * ssp;
    float ni = i * cp + r * ssp;
    r = nr; i = ni;
}

template<int Q>
__device__ __forceinline__ void apply_rz_t(float cp, float sp, float ar[4], float ai[4], int lane) {
    if constexpr (Q == 0) {
        rz_amp(cp, -sp, ar[0], ai[0]); rz_amp(cp,  sp, ar[1], ai[1]);
        rz_amp(cp, -sp, ar[2], ai[2]); rz_amp(cp,  sp, ar[3], ai[3]);
    } else if constexpr (Q == 1) {
        rz_amp(cp, -sp, ar[0], ai[0]); rz_amp(cp, -sp, ar[1], ai[1]);
        rz_amp(cp,  sp, ar[2], ai[2]); rz_amp(cp,  sp, ar[3], ai[3]);
    } else {
        float ssp = (lane & (1 << (Q - 2))) ? sp : -sp;
#pragma unroll
        for (int j = 0; j < 4; ++j) rz_amp(cp, ssp, ar[j], ai[j]);
    }
}

// CNOT(c, (c+1)%8)
template<int C>
__device__ __forceinline__ void apply_cnot_t(float ar[4], float ai[4], int lane) {
    if constexpr (C == 0) {
        float t;
        t = ar[1]; ar[1] = ar[3]; ar[3] = t;
        t = ai[1]; ai[1] = ai[3]; ai[3] = t;
    } else if constexpr (C == 1) {
        ar[2] = xorlane<1>(ar[2], lane); ai[2] = xorlane<1>(ai[2], lane);
        ar[3] = xorlane<1>(ar[3], lane); ai[3] = xorlane<1>(ai[3], lane);
    } else if constexpr (C == 7) {
        bool hi = (lane & 32) != 0;
        float t0 = ar[0]; ar[0] = hi ? ar[1] : ar[0]; ar[1] = hi ? t0 : ar[1];
        float u0 = ai[0]; ai[0] = hi ? ai[1] : ai[0]; ai[1] = hi ? u0 : ai[1];
        float t2 = ar[2]; ar[2] = hi ? ar[3] : ar[2]; ar[3] = hi ? t2 : ar[3];
        float u2 = ai[2]; ai[2] = hi ? ai[3] : ai[2]; ai[3] = hi ? u2 : ai[3];
    } else {
        constexpr int cm = 1 << (C - 2);
        constexpr int tm = 1 << (C - 1);
        bool hi = (lane & cm) != 0;
#pragma unroll
        for (int j = 0; j < 4; ++j) {
            float pr = xorlane<tm>(ar[j], lane);
            float pq = xorlane<tm>(ai[j], lane);
            ar[j] = hi ? pr : ar[j];
            ai[j] = hi ? pq : ai[j];
        }
    }
}

#define CMUL(rr, ri, xr, xi, yr, yi) { float _tr = (xr)*(yr) - (xi)*(yi); \
                                       float _ti = (xr)*(yi) + (xi)*(yr); \
                                       rr = _tr; ri = _ti; }

// ============ Kernel A: reduced circuit -> z[B][8] ============
// DIAGNOSTIC ROUND: grid is 4x the needed blocks; bid = blockIdx.x % nblk so
// the extra blocks redo identical work (benign identical-value writes). This
// makes the A dispatch ~4x longer so it surfaces in the rocprof top-5 with
// full counters, and dur_us-30 ~= 3*A gives A's true cost.
__global__ __launch_bounds__(256) void qcircuit_z(
    const float* __restrict__ x,        // [B,8]
    const float* __restrict__ qw,       // [3,8,2]
    float* __restrict__ zws,            // [B,8]
    int B, int nblk)
{
    __shared__ float4 tab[NLAYERS * NQ];

    int tid = threadIdx.x;
    if (tid < NLAYERS * NQ) {
        float w0 = 0.5f * qw[tid * 2 + 0];
        float w1 = 0.5f * qw[tid * 2 + 1];
        if (tid < 8)
            tab[tid] = make_float4(w0, 0.f, __cosf(w1), __sinf(w1));
        else
            tab[tid] = make_float4(__cosf(w0), __sinf(w0), __cosf(w1), __sinf(w1));
    }
    __syncthreads();

    int lane = tid & 63;
    int wid  = tid >> 6;
    int bid = blockIdx.x % nblk;
    int sample = bid * 4 + wid;
    if (sample >= B) return;

    // ---- load x row, normalize ----
    const float4* x4 = (const float4*)(x + sample * 8);
    float4 xa = x4[0], xb = x4[1];
    float xs[8] = {xa.x, xa.y, xa.z, xa.w, xb.x, xb.y, xb.z, xb.w};
    float xmin = xs[0], xmax = xs[0];
#pragma unroll
    for (int q = 1; q < 8; ++q) {
        xmin = fminf(xmin, xs[q]);
        xmax = fmaxf(xmax, xs[q]);
    }
    float inv_pi2 = 1.5707963267948966f / (xmax - xmin + 1e-8f);

    // per-qubit trig (encoding + layer0 RY fold)
    float cc[8], ss[8], cw[8], sw[8];
#pragma unroll
    for (int q = 0; q < 8; ++q) {
        float4 t0 = tab[q];
        float a = fmaf(xs[q] - xmin, inv_pi2, t0.x);
        cc[q] = __cosf(a);
        ss[q] = __sinf(a);
        cw[q] = t0.z;
        sw[q] = t0.w;
    }

    // ---- state construction with ring0 folded in (selector bits) ----
    float plr, pli;
    {
        int b = ((lane >> 0) ^ (lane >> 1)) & 1;     // q=3: l0^l1
        float r = b ? ss[3] : cc[3];
        plr = r * cw[3];
        pli = b ? r * sw[3] : -r * sw[3];
    }
#pragma unroll
    for (int q = 4; q < 8; ++q) {
        int b = ((lane >> (q - 3)) ^ (lane >> (q - 2))) & 1;
        float r = b ? ss[q] : cc[q];
        float fr = r * cw[q];
        float fi = b ? r * sw[q] : -r * sw[q];
        CMUL(plr, pli, plr, pli, fr, fi);
    }

    int u = (lane >> 5) & 1;
    int v = lane & 1;

    float r0A = u ? ss[0] : cc[0];
    float f0Ar = r0A * cw[0], f0Ai = (u ? r0A : -r0A) * sw[0];
    float r0B = u ? cc[0] : ss[0];
    float f0Br = r0B * cw[0], f0Bi = (u ? -r0B : r0B) * sw[0];
    float r1A = u ? ss[1] : cc[1];
    float f1Ar = r1A * cw[1], f1Ai = (u ? r1A : -r1A) * sw[1];
    float r1B = u ? cc[1] : ss[1];
    float f1Br = r1B * cw[1], f1Bi = (u ? -r1B : r1B) * sw[1];
    float r2A = v ? ss[2] : cc[2];
    float f2Ar = r2A * cw[2], f2Ai = (v ? r2A : -r2A) * sw[2];
    float r2B = v ? cc[2] : ss[2];
    float f2Br = r2B * cw[2], f2Bi = (v ? -r2B : r2B) * sw[2];

    float tAAr, tAAi, tBBr, tBBi, tABr, tABi, tBAr, tBAi;
    CMUL(tAAr, tAAi, f0Ar, f0Ai, f1Ar, f1Ai);
    CMUL(tBBr, tBBi, f0Br, f0Bi, f1Br, f1Bi);
    CMUL(tABr, tABi, f0Ar, f0Ai, f1Br, f1Bi);
    CMUL(tBAr, tBAi, f0Br, f0Bi, f1Ar, f1Ai);

    float ar[4], ai[4];
    CMUL(ar[0], ai[0], tAAr, tAAi, f2Ar, f2Ai);
    CMUL(ar[1], ai[1], tBBr, tBBi, f2Ar, f2Ai);
    CMUL(ar[2], ai[2], tABr, tABi, f2Br, f2Bi);
    CMUL(ar[3], ai[3], tBAr, tBAi, f2Br, f2Bi);
#pragma unroll
    for (int j = 0; j < 4; ++j) {
        CMUL(ar[j], ai[j], ar[j], ai[j], plr, pli);
    }

    // ---- layer 1: RY + RZ all qubits, then CNOT ring ----
    {
        float4 t;
        t = tab[8];  apply_ry_t<0>(t.x, t.y, ar, ai, lane); apply_rz_t<0>(t.z, t.w, ar, ai, lane);
        t = tab[9];  apply_ry_t<1>(t.x, t.y, ar, ai, lane); apply_rz_t<1>(t.z, t.w, ar, ai, lane);
        t = tab[10]; apply_ry_t<2>(t.x, t.y, ar, ai, lane); apply_rz_t<2>(t.z, t.w, ar, ai, lane);
        t = tab[11]; apply_ry_t<3>(t.x, t.y, ar, ai, lane); apply_rz_t<3>(t.z, t.w, ar, ai, lane);
        t = tab[12]; apply_ry_t<4>(t.x, t.y, ar, ai, lane); apply_rz_t<4>(t.z, t.w, ar, ai, lane);
        t = tab[13]; apply_ry_t<5>(t.x, t.y, ar, ai, lane); apply_rz_t<5>(t.z, t.w, ar, ai, lane);
        t = tab[14]; apply_ry_t<6>(t.x, t.y, ar, ai, lane); apply_rz_t<6>(t.z, t.w, ar, ai, lane);
        t = tab[15]; apply_ry_t<7>(t.x, t.y, ar, ai, lane); apply_rz_t<7>(t.z, t.w, ar, ai, lane);
    }
    apply_cnot_t<0>(ar, ai, lane);
    apply_cnot_t<1>(ar, ai, lane);
    apply_cnot_t<2>(ar, ai, lane);
    apply_cnot_t<3>(ar, ai, lane);
    apply_cnot_t<4>(ar, ai, lane);
    apply_cnot_t<5>(ar, ai, lane);
    apply_cnot_t<6>(ar, ai, lane);
    apply_cnot_t<7>(ar, ai, lane);

    // ---- layer 2: RY only (RZ + ring folded into measurement) ----
    {
        float4 t;
        t = tab[16]; apply_ry_t<0>(t.x, t.y, ar, ai, lane);
        t = tab[17]; apply_ry_t<1>(t.x, t.y, ar, ai, lane);
        t = tab[18]; apply_ry_t<2>(t.x, t.y, ar, ai, lane);
        t = tab[19]; apply_ry_t<3>(t.x, t.y, ar, ai, lane);
        t = tab[20]; apply_ry_t<4>(t.x, t.y, ar, ai, lane);
        t = tab[21]; apply_ry_t<5>(t.x, t.y, ar, ai, lane);
        t = tab[22]; apply_ry_t<6>(t.x, t.y, ar, ai, lane);
        t = tab[23]; apply_ry_t<7>(t.x, t.y, ar, ai, lane);
    }

    // ---- measurement through the (deleted) final ring ----
    float p0 = ar[0] * ar[0] + ai[0] * ai[0];
    float p1 = ar[1] * ar[1] + ai[1] * ai[1];
    float p2 = ar[2] * ar[2] + ai[2] * ai[2];
    float p3 = ar[3] * ar[3] + ai[3] * ai[3];

    float T33 = (p0 - p1) - (p2 - p3);   // parity(3&j)
    float T2  = (p0 + p1) - (p2 + p3);   // parity(2&j)

    int pp1 = lane & 1;
    int pp2 = pp1 ^ ((lane >> 1) & 1);
    int pp3 = pp2 ^ ((lane >> 2) & 1);
    int pp4 = pp3 ^ ((lane >> 3) & 1);
    int pp5 = pp4 ^ ((lane >> 4) & 1);
    int pp6 = pp5 ^ ((lane >> 5) & 1);

    float z0 = wave_sum63(pp6 ? -T2  : T2);
    float z1 = wave_sum63(T33);
    float z2 = wave_sum63(pp1 ? -T33 : T33);
    float z3 = wave_sum63(pp2 ? -T33 : T33);
    float z4 = wave_sum63(pp3 ? -T33 : T33);
    float z5 = wave_sum63(pp4 ? -T33 : T33);
    float z6 = wave_sum63(pp5 ? -T33 : T33);
    float z7 = wave_sum63(pp6 ? -T33 : T33);

    if (lane == 63) {
        *(float4*)(zws + sample * 8)     = make_float4(z0, z1, z2, z3);
        *(float4*)(zws + sample * 8 + 4) = make_float4(z4, z5, z6, z7);
    }
}

// ============ Kernel B: z -> out (register-blocked MLP, spill-safe) ============
__global__ __launch_bounds__(256) void qmlp2(
    const float* __restrict__ zws,      // [B,8]
    const float* __restrict__ W1,       // [8,64]
    const float* __restrict__ b1,       // [64]
    const float* __restrict__ W2,       // [64,256]
    const float* __restrict__ b2,       // [256]
    float* __restrict__ out,            // [B,256]
    int B)
{
    __shared__ float h_lds[16][64];

    int t = threadIdx.x;
    int sbase = blockIdx.x * 16;

    // phase 1: h[16][64] tile
    {
        int s_l = t >> 4;
        int i_l = (t & 15) * 4;
        int srow = sbase + s_l; if (srow >= B) srow = B - 1;
        const float* zr = zws + srow * 8;
        float4 za = *(const float4*)zr;
        float4 zb = *(const float4*)(zr + 4);
        float zq[8] = {za.x, za.y, za.z, za.w, zb.x, zb.y, zb.z, zb.w};
        float4 acc = *(const float4*)(b1 + i_l);
#pragma unroll
        for (int q = 0; q < 8; ++q) {
            float4 w = *(const float4*)(W1 + q * 64 + i_l);
            acc.x += zq[q] * w.x; acc.y += zq[q] * w.y;
            acc.z += zq[q] * w.z; acc.w += zq[q] * w.w;
        }
        acc.x = fmaxf(acc.x, 0.f); acc.y = fmaxf(acc.y, 0.f);
        acc.z = fmaxf(acc.z, 0.f); acc.w = fmaxf(acc.w, 0.f);
        *(float4*)&h_lds[s_l][i_l] = acc;
    }
    __syncthreads();

    // phase 2: out = h @ W2 + b2 ; 4 samples x 4 cols per thread
    int sg = t >> 6;
    int c4 = (t & 63) * 4;
    float4 bb = *(const float4*)(b2 + c4);
    float4 a0 = bb, a1 = bb, a2 = bb, a3 = bb;
    const int sO = sg * 4;

#pragma unroll 2
    for (int i4 = 0; i4 < 16; ++i4) {
        const float* wrow = W2 + i4 * 4 * 256 + c4;
        float4 w0 = *(const float4*)(wrow);
        float4 w1 = *(const float4*)(wrow + 256);
        float4 w2 = *(const float4*)(wrow + 512);
        float4 w3 = *(const float4*)(wrow + 768);
        float4 h0 = *(const float4*)&h_lds[sO + 0][i4 * 4];
        float4 h1 = *(const float4*)&h_lds[sO + 1][i4 * 4];
        float4 h2 = *(const float4*)&h_lds[sO + 2][i4 * 4];
        float4 h3 = *(const float4*)&h_lds[sO + 3][i4 * 4];

        a0.x += h0.x*w0.x + h0.y*w1.x + h0.z*w2.x + h0.w*w3.x;
        a0.y += h0.x*w0.y + h0.y*w1.y + h0.z*w2.y + h0.w*w3.y;
        a0.z += h0.x*w0.z + h0.y*w1.z + h0.z*w2.z + h0.w*w3.z;
        a0.w += h0.x*w0.w + h0.y*w1.w + h0.z*w2.w + h0.w*w3.w;

        a1.x += h1.x*w0.x + h1.y*w1.x + h1.z*w2.x + h1.w*w3.x;
        a1.y += h1.x*w0.y + h1.y*w1.y + h1.z*w2.y + h1.w*w3.y;
        a1.z += h1.x*w0.z + h1.y*w1.z + h1.z*w2.z + h1.w*w3.z;
        a1.w += h1.x*w0.w + h1.y*w1.w + h1.z*w2.w + h1.w*w3.w;

        a2.x += h2.x*w0.x + h2.y*w1.x + h2.z*w2.x + h2.w*w3.x;
        a2.y += h2.x*w0.y + h2.y*w1.y + h2.z*w2.y + h2.w*w3.y;
        a2.z += h2.x*w0.z + h2.y*w1.z + h2.z*w2.z + h2.w*w3.z;
        a2.w += h2.x*w0.w + h2.y*w1.w + h2.z*w2.w + h2.w*w3.w;

        a3.x += h3.x*w0.x + h3.y*w1.x + h3.z*w2.x + h3.w*w3.x;
        a3.y += h3.x*w0.y + h3.y*w1.y + h3.z*w2.y + h3.w*w3.y;
        a3.z += h3.x*w0.z + h3.y*w1.z + h3.z*w2.z + h3.w*w3.z;
        a3.w += h3.x*w0.w + h3.y*w1.w + h3.z*w2.w + h3.w*w3.w;
    }

    int srow = sbase + sO;
    if (srow + 0 < B) *(float4*)(out + (srow + 0) * 256 + c4) = a0;
    if (srow + 1 < B) *(float4*)(out + (srow + 1) * 256 + c4) = a1;
    if (srow + 2 < B) *(float4*)(out + (srow + 2) * 256 + c4) = a2;
    if (srow + 3 < B) *(float4*)(out + (srow + 3) * 256 + c4) = a3;
}

extern "C" void kernel_launch(void* const* d_in, const int* in_sizes, int n_in,
                              void* d_out, int out_size, void* d_ws, size_t ws_size,
                              hipStream_t stream) {
    const float* x  = (const float*)d_in[0];
    const float* qw = (const float*)d_in[1];
    const float* W1 = (const float*)d_in[2];
    const float* b1 = (const float*)d_in[3];
    const float* W2 = (const float*)d_in[4];
    const float* b2 = (const float*)d_in[5];
    float* out = (float*)d_out;
    float* zws = (float*)d_ws;          // needs B*8*4 = 256 KiB

    int B = in_sizes[0] / NQ;           // 8192
    int nblk = (B + 3) / 4;             // 2048 real blocks

    // DIAGNOSTIC: 4x redundant grid so the A dispatch exceeds the 38us harness
    // fills and surfaces its counter row in top-5. Extra blocks write identical
    // values (deterministic).
    qcircuit_z<<<nblk * 4, 256, 0, stream>>>(x, qw, zws, B, nblk);
    qmlp2<<<(B + 15) / 16, 256, 0, stream>>>(zws, W1, b1, W2, b2, out, B);
}

// Round 9
// 24.204 us; speedup vs baseline: 3.0390x; 3.0390x over previous
//
#include <hip/hip_runtime.h>

#define NQ 8
#define NLAYERS 3

typedef unsigned int uint2ev __attribute__((ext_vector_type(2)));

// ---- row-local xor exchange (16-lane rows), zero DS ops ----
template<int MASK>
__device__ __forceinline__ float xorlane(float v, int r) {
    if constexpr (MASK == 1) {
        return __int_as_float(__builtin_amdgcn_mov_dpp(__float_as_int(v), 0xB1, 0xF, 0xF, false)); // quad_perm [1,0,3,2]
    } else if constexpr (MASK == 2) {
        return __int_as_float(__builtin_amdgcn_mov_dpp(__float_as_int(v), 0x4E, 0xF, 0xF, false)); // quad_perm [2,3,0,1]
    } else if constexpr (MASK == 4) {
        float a = __int_as_float(__builtin_amdgcn_update_dpp(0, __float_as_int(v), 0x114, 0xF, 0xF, false)); // row_shr:4
        float b = __int_as_float(__builtin_amdgcn_update_dpp(0, __float_as_int(v), 0x104, 0xF, 0xF, false)); // row_shl:4
        return (r & 4) ? a : b;
    } else if constexpr (MASK == 8) {
        return __int_as_float(__builtin_amdgcn_mov_dpp(__float_as_int(v), 0x128, 0xF, 0xF, false)); // row_ror:8 == xor 8 in row16
    }
}

// ---- DPP-fused row16 sum; row total lands in lane r=15 of each row ----
template<int CTRL>
__device__ __forceinline__ float dpp_add_stage(float v) {
    int moved = __builtin_amdgcn_update_dpp(0, __float_as_int(v), CTRL, 0xF, 0xF, false);
    return v + __int_as_float(moved);
}
__device__ __forceinline__ float rowsum15(float v) {
    v = dpp_add_stage<0x111>(v);   // row_shr:1
    v = dpp_add_stage<0x112>(v);   // row_shr:2
    v = dpp_add_stage<0x114>(v);   // row_shr:4
    v = dpp_add_stage<0x118>(v);   // row_shr:8
    return v;                      // lane 15 of each 16-row has the row sum
}

__device__ __forceinline__ void ry_pair(float c, float s, float& a0, float& a1) {
    float n0 = c * a0 - s * a1;
    float n1 = s * a0 + c * a1;
    a0 = n0; a1 = n1;
}

__device__ __forceinline__ void rz_amp(float cp, float ssp, float& re, float& im) {
    float nr = re * cp - im * ssp;
    float ni = im * cp + re * ssp;
    re = nr; im = ni;
}

// qubits 0..3 -> j bits 0..3 (16 amps/lane); qubits 4..7 -> row-lane bits r0..r3
template<int Q>
__device__ __forceinline__ void ry16(float c, float s, float ar[16], float ai[16], int r) {
    if constexpr (Q < 4) {
        constexpr int M = 1 << Q;
#pragma unroll
        for (int j = 0; j < 16; ++j) if (!(j & M)) {
            ry_pair(c, s, ar[j], ar[j | M]);
            ry_pair(c, s, ai[j], ai[j | M]);
        }
    } else {
        constexpr int LM = 1 << (Q - 4);
        float sgn = (r & LM) ? s : -s;
#pragma unroll
        for (int j = 0; j < 16; ++j) {
            float pr = xorlane<LM>(ar[j], r);
            float pi = xorlane<LM>(ai[j], r);
            ar[j] = c * ar[j] + sgn * pr;
            ai[j] = c * ai[j] + sgn * pi;
        }
    }
}

template<int Q>
__device__ __forceinline__ void rz16(float cp, float sp, float ar[16], float ai[16], int r) {
    if constexpr (Q < 4) {
#pragma unroll
        for (int j = 0; j < 16; ++j) {
            float ssp = ((j >> Q) & 1) ? sp : -sp;
            rz_amp(cp, ssp, ar[j], ai[j]);
        }
    } else {
        float ssp = (r & (1 << (Q - 4))) ? sp : -sp;
#pragma unroll
        for (int j = 0; j < 16; ++j) rz_amp(cp, ssp, ar[j], ai[j]);
    }
}

#define SWAP2(a, b) { float _t = a; a = b; b = _t; }

// ring1: CNOT(0,1),(1,2),(2,3),(3,4),(4,5),(5,6),(6,7),(7,0)
__device__ __forceinline__ void ring16(float ar[16], float ai[16], int r) {
    // (0,1): j0=1 -> flip j1: swap (1,3),(5,7),(9,11),(13,15)   [free renames]
    SWAP2(ar[1], ar[3]);  SWAP2(ai[1], ai[3]);
    SWAP2(ar[5], ar[7]);  SWAP2(ai[5], ai[7]);
    SWAP2(ar[9], ar[11]); SWAP2(ai[9], ai[11]);
    SWAP2(ar[13], ar[15]); SWAP2(ai[13], ai[15]);
    // (1,2): j1=1 -> flip j2: swap (2,6),(3,7),(10,14),(11,15)
    SWAP2(ar[2], ar[6]);  SWAP2(ai[2], ai[6]);
    SWAP2(ar[3], ar[7]);  SWAP2(ai[3], ai[7]);
    SWAP2(ar[10], ar[14]); SWAP2(ai[10], ai[14]);
    SWAP2(ar[11], ar[15]); SWAP2(ai[11], ai[15]);
    // (2,3): j2=1 -> flip j3: swap (4,12),(5,13),(6,14),(7,15)
    SWAP2(ar[4], ar[12]); SWAP2(ai[4], ai[12]);
    SWAP2(ar[5], ar[13]); SWAP2(ai[5], ai[13]);
    SWAP2(ar[6], ar[14]); SWAP2(ai[6], ai[14]);
    SWAP2(ar[7], ar[15]); SWAP2(ai[7], ai[15]);
    // (3,4): j3=1 -> flip r0: unconditional exchange across lane-mask 1 for j=8..15
#pragma unroll
    for (int j = 8; j < 16; ++j) {
        ar[j] = xorlane<1>(ar[j], r);
        ai[j] = xorlane<1>(ai[j], r);
    }
    // (4,5): ctrl r0, tgt r1
    {
        bool hi = (r & 1) != 0;
#pragma unroll
        for (int j = 0; j < 16; ++j) {
            float pr = xorlane<2>(ar[j], r);
            float pi = xorlane<2>(ai[j], r);
            ar[j] = hi ? pr : ar[j];
            ai[j] = hi ? pi : ai[j];
        }
    }
    // (5,6): ctrl r1, tgt r2
    {
        bool hi = (r & 2) != 0;
#pragma unroll
        for (int j = 0; j < 16; ++j) {
            float pr = xorlane<4>(ar[j], r);
            float pi = xorlane<4>(ai[j], r);
            ar[j] = hi ? pr : ar[j];
            ai[j] = hi ? pi : ai[j];
        }
    }
    // (6,7): ctrl r2, tgt r3
    {
        bool hi = (r & 4) != 0;
#pragma unroll
        for (int j = 0; j < 16; ++j) {
            float pr = xorlane<8>(ar[j], r);
            float pi = xorlane<8>(ai[j], r);
            ar[j] = hi ? pr : ar[j];
            ai[j] = hi ? pi : ai[j];
        }
    }
    // (7,0): ctrl r3, tgt j0: lanes r3=1 swap local pairs j <-> j^1
    {
        bool hi = (r & 8) != 0;
#pragma unroll
        for (int j = 0; j < 16; j += 2) {
            float t0r = ar[j], t1r = ar[j + 1];
            ar[j]     = hi ? t1r : t0r;
            ar[j + 1] = hi ? t0r : t1r;
            float t0i = ai[j], t1i = ai[j + 1];
            ai[j]     = hi ? t1i : t0i;
            ai[j + 1] = hi ? t0i : t1i;
        }
    }
}

#define CMUL(rr, ri, xr, xi, yr, yi) { float _tr = (xr)*(yr) - (xi)*(yi); \
                                       float _ti = (xr)*(yi) + (xi)*(yr); \
                                       rr = _tr; ri = _ti; }

// ============ Kernel A: 4 samples/wave (16 lanes each) -> z[B][8] ============
// Exact reductions carried from round 7 (verified): layer0 RY+RZ folded into
// encoding product state; ring0 deleted via selectors s0=j0^r3, s1=j0^j1^r3,
// s2=j1^j2, s3=j2^j3, s4=j3^r0, s5=r0^r1, s6=r1^r2, s7=r2^r3; layer2 RZ
// deleted; ring2 folded into measurement prefix-parity masks.
__global__ __launch_bounds__(256) void qcircuit_z(
    const float* __restrict__ x,        // [B,8]
    const float* __restrict__ qw,       // [3,8,2]
    float* __restrict__ zws,            // [B,8]
    int B)
{
    __shared__ float4 tab[NLAYERS * NQ];

    int tid = threadIdx.x;
    if (tid < NLAYERS * NQ) {
        float w0 = 0.5f * qw[tid * 2 + 0];
        float w1 = 0.5f * qw[tid * 2 + 1];
        if (tid < 8)
            tab[tid] = make_float4(w0, 0.f, __cosf(w1), __sinf(w1));
        else
            tab[tid] = make_float4(__cosf(w0), __sinf(w0), __cosf(w1), __sinf(w1));
    }
    __syncthreads();

    int lane = tid & 63;
    int wid  = tid >> 6;
    int g    = lane >> 4;               // sample group in wave
    int r    = lane & 15;               // row-lane bits r0..r3
    int sample = (blockIdx.x * 4 + wid) * 4 + g;
    if (sample >= B) return;

    // ---- per-lane encode of its own sample ----
    const float4* x4 = (const float4*)(x + sample * 8);
    float4 xa = x4[0], xb = x4[1];
    float xs[8] = {xa.x, xa.y, xa.z, xa.w, xb.x, xb.y, xb.z, xb.w};
    float xmin = xs[0], xmax = xs[0];
#pragma unroll
    for (int q = 1; q < 8; ++q) {
        xmin = fminf(xmin, xs[q]);
        xmax = fmaxf(xmax, xs[q]);
    }
    float inv_pi2 = 1.5707963267948966f / (xmax - xmin + 1e-8f);

    float cc[8], ss[8], cw[8], sw[8];
#pragma unroll
    for (int q = 0; q < 8; ++q) {
        float4 t0 = tab[q];
        float a = fmaf(xs[q] - xmin, inv_pi2, t0.x);
        cc[q] = __cosf(a);
        ss[q] = __sinf(a);
        cw[q] = t0.z;
        sw[q] = t0.w;
    }

    // f_q(b) = ((b? ss:cc)*cw, (b? +1:-1)*(b? ss:cc)*sw)
    int r0v = r & 1, r3v = (r >> 3) & 1;

    // X0[k]=f0(k^r3), X1[k]=f1(k^r3), X2[k]=f2(k), X3[k]=f3(k), X4[k]=f4(k^r0)
    float X0r[2], X0i[2], X1r[2], X1i[2], X2r[2], X2i[2], X3r[2], X3i[2], X4r[2], X4i[2];
#pragma unroll
    for (int k = 0; k < 2; ++k) {
        { int b = k ^ r3v; float rr = b ? ss[0] : cc[0];
          X0r[k] = rr * cw[0]; X0i[k] = (b ? rr : -rr) * sw[0]; }
        { int b = k ^ r3v; float rr = b ? ss[1] : cc[1];
          X1r[k] = rr * cw[1]; X1i[k] = (b ? rr : -rr) * sw[1]; }
        { int b = k;        float rr = b ? ss[2] : cc[2];
          X2r[k] = rr * cw[2]; X2i[k] = (b ? rr : -rr) * sw[2]; }
        { int b = k;        float rr = b ? ss[3] : cc[3];
          X3r[k] = rr * cw[3]; X3i[k] = (b ? rr : -rr) * sw[3]; }
        { int b = k ^ r0v;  float rr = b ? ss[4] : cc[4];
          X4r[k] = rr * cw[4]; X4i[k] = (b ? rr : -rr) * sw[4]; }
    }

    // plane = f5(r0^r1) * f6(r1^r2) * f7(r2^r3)
    float plr, pli;
    {
        int b5 = (r ^ (r >> 1)) & 1;
        int b6 = ((r >> 1) ^ (r >> 2)) & 1;
        int b7 = ((r >> 2) ^ (r >> 3)) & 1;
        float r5 = b5 ? ss[5] : cc[5];
        float f5r = r5 * cw[5], f5i = (b5 ? r5 : -r5) * sw[5];
        float r6 = b6 ? ss[6] : cc[6];
        float f6r = r6 * cw[6], f6i = (b6 ? r6 : -r6) * sw[6];
        float r7 = b7 ? ss[7] : cc[7];
        float f7r = r7 * cw[7], f7i = (b7 ? r7 : -r7) * sw[7];
        CMUL(plr, pli, f5r, f5i, f6r, f6i);
        CMUL(plr, pli, plr, pli, f7r, f7i);
    }

    // PP[j0][j1] = plane * X0[j0] * X1[j0^j1]
    float PPr[2][2], PPi[2][2];
    {
        float t0r, t0i, t1r, t1i;
        CMUL(t0r, t0i, plr, pli, X0r[0], X0i[0]);
        CMUL(t1r, t1i, plr, pli, X0r[1], X0i[1]);
        CMUL(PPr[0][0], PPi[0][0], t0r, t0i, X1r[0], X1i[0]);
        CMUL(PPr[0][1], PPi[0][1], t0r, t0i, X1r[1], X1i[1]);
        CMUL(PPr[1][0], PPi[1][0], t1r, t1i, X1r[1], X1i[1]);
        CMUL(PPr[1][1], PPi[1][1], t1r, t1i, X1r[0], X1i[0]);
    }
    // Q34[j2][j3] = X3[j2^j3] * X4[j3]
    float Qr[2][2], Qi[2][2];
    CMUL(Qr[0][0], Qi[0][0], X3r[0], X3i[0], X4r[0], X4i[0]);
    CMUL(Qr[0][1], Qi[0][1], X3r[1], X3i[1], X4r[1], X4i[1]);
    CMUL(Qr[1][0], Qi[1][0], X3r[1], X3i[1], X4r[0], X4i[0]);
    CMUL(Qr[1][1], Qi[1][1], X3r[0], X3i[0], X4r[1], X4i[1]);
    // R[j1][j2][j3] = X2[j1^j2] * Q34[j2][j3]
    float Rr[2][2][2], Ri[2][2][2];
#pragma unroll
    for (int j1 = 0; j1 < 2; ++j1)
#pragma unroll
        for (int j2 = 0; j2 < 2; ++j2)
#pragma unroll
            for (int j3 = 0; j3 < 2; ++j3) {
                int k = j1 ^ j2;
                CMUL(Rr[j1][j2][j3], Ri[j1][j2][j3], X2r[k], X2i[k], Qr[j2][j3], Qi[j2][j3]);
            }

    // amp[j0 + 2j1 + 4j2 + 8j3] = PP[j0][j1] * R[j1][j2][j3]
    float ar[16], ai[16];
#pragma unroll
    for (int j3 = 0; j3 < 2; ++j3)
#pragma unroll
        for (int j2 = 0; j2 < 2; ++j2)
#pragma unroll
            for (int j1 = 0; j1 < 2; ++j1)
#pragma unroll
                for (int j0 = 0; j0 < 2; ++j0) {
                    int j = j0 + 2 * j1 + 4 * j2 + 8 * j3;
                    CMUL(ar[j], ai[j], PPr[j0][j1], PPi[j0][j1], Rr[j1][j2][j3], Ri[j1][j2][j3]);
                }

    // ---- layer 1: RY + RZ all qubits ----
    {
        float4 t;
        t = tab[8];  ry16<0>(t.x, t.y, ar, ai, r); rz16<0>(t.z, t.w, ar, ai, r);
        t = tab[9];  ry16<1>(t.x, t.y, ar, ai, r); rz16<1>(t.z, t.w, ar, ai, r);
        t = tab[10]; ry16<2>(t.x, t.y, ar, ai, r); rz16<2>(t.z, t.w, ar, ai, r);
        t = tab[11]; ry16<3>(t.x, t.y, ar, ai, r); rz16<3>(t.z, t.w, ar, ai, r);
        t = tab[12]; ry16<4>(t.x, t.y, ar, ai, r); rz16<4>(t.z, t.w, ar, ai, r);
        t = tab[13]; ry16<5>(t.x, t.y, ar, ai, r); rz16<5>(t.z, t.w, ar, ai, r);
        t = tab[14]; ry16<6>(t.x, t.y, ar, ai, r); rz16<6>(t.z, t.w, ar, ai, r);
        t = tab[15]; ry16<7>(t.x, t.y, ar, ai, r); rz16<7>(t.z, t.w, ar, ai, r);
    }
    // ---- ring 1 ----
    ring16(ar, ai, r);
    // ---- layer 2: RY only ----
    {
        float4 t;
        t = tab[16]; ry16<0>(t.x, t.y, ar, ai, r);
        t = tab[17]; ry16<1>(t.x, t.y, ar, ai, r);
        t = tab[18]; ry16<2>(t.x, t.y, ar, ai, r);
        t = tab[19]; ry16<3>(t.x, t.y, ar, ai, r);
        t = tab[20]; ry16<4>(t.x, t.y, ar, ai, r);
        t = tab[21]; ry16<5>(t.x, t.y, ar, ai, r);
        t = tab[22]; ry16<6>(t.x, t.y, ar, ai, r);
        t = tab[23]; ry16<7>(t.x, t.y, ar, ai, r);
    }

    // ---- measurement through folded ring2: masks m0=0xFE, m_q=2^{q+1}-1 ----
    float P[16];
#pragma unroll
    for (int j = 0; j < 16; ++j) P[j] = ar[j] * ar[j] + ai[j] * ai[j];

    float Sp[8], Dp[8];
#pragma unroll
    for (int k = 0; k < 8; ++k) {
        Sp[k] = P[2 * k] + P[2 * k + 1];
        Dp[k] = P[2 * k] - P[2 * k + 1];
    }
    // popc-parities of k (bits j1j2j3): 0:+ 1:- 2:- 3:+ 4:- 5:+ 6:+ 7:-
    float U0 = ((Sp[0] - Sp[1]) - (Sp[2] - Sp[3])) - ((Sp[4] - Sp[5]) - (Sp[6] - Sp[7]));
    float U3 = ((Dp[0] - Dp[1]) - (Dp[2] - Dp[3])) - ((Dp[4] - Dp[5]) - (Dp[6] - Dp[7]));
    // U1: sign (-1)^{k&1}
    float U1 = (Dp[0] - Dp[1]) + (Dp[2] - Dp[3]) + (Dp[4] - Dp[5]) + (Dp[6] - Dp[7]);
    // U2: sign (-1)^{popc(k&3)}: + - - +  + - - +
    float U2 = ((Dp[0] - Dp[1]) - (Dp[2] - Dp[3])) + ((Dp[4] - Dp[5]) - (Dp[6] - Dp[7]));

    int p1 = r & 1;
    int p2 = (r ^ (r >> 1)) & 1;
    int p3 = (r ^ (r >> 1) ^ (r >> 2)) & 1;
    int p4 = (r ^ (r >> 1) ^ (r >> 2) ^ (r >> 3)) & 1;

    float z0 = rowsum15(p4 ? -U0 : U0);
    float z1 = rowsum15(U1);
    float z2 = rowsum15(U2);
    float z3 = rowsum15(U3);
    float z4 = rowsum15(p1 ? -U3 : U3);
    float z5 = rowsum15(p2 ? -U3 : U3);
    float z6 = rowsum15(p3 ? -U3 : U3);
    float z7 = rowsum15(p4 ? -U3 : U3);

    if (r == 15) {
        *(float4*)(zws + sample * 8)     = make_float4(z0, z1, z2, z3);
        *(float4*)(zws + sample * 8 + 4) = make_float4(z4, z5, z6, z7);
    }
}

// ============ Kernel B: z -> out (register-blocked MLP, spill-safe) ============
__global__ __launch_bounds__(256) void qmlp2(
    const float* __restrict__ zws,      // [B,8]
    const float* __restrict__ W1,       // [8,64]
    const float* __restrict__ b1,       // [64]
    const float* __restrict__ W2,       // [64,256]
    const float* __restrict__ b2,       // [256]
    float* __restrict__ out,            // [B,256]
    int B)
{
    __shared__ float h_lds[16][64];

    int t = threadIdx.x;
    int sbase = blockIdx.x * 16;

    // phase 1: h[16][64] tile
    {
        int s_l = t >> 4;
        int i_l = (t & 15) * 4;
        int srow = sbase + s_l; if (srow >= B) srow = B - 1;
        const float* zr = zws + srow * 8;
        float4 za = *(const float4*)zr;
        float4 zb = *(const float4*)(zr + 4);
        float zq[8] = {za.x, za.y, za.z, za.w, zb.x, zb.y, zb.z, zb.w};
        float4 acc = *(const float4*)(b1 + i_l);
#pragma unroll
        for (int q = 0; q < 8; ++q) {
            float4 w = *(const float4*)(W1 + q * 64 + i_l);
            acc.x += zq[q] * w.x; acc.y += zq[q] * w.y;
            acc.z += zq[q] * w.z; acc.w += zq[q] * w.w;
        }
        acc.x = fmaxf(acc.x, 0.f); acc.y = fmaxf(acc.y, 0.f);
        acc.z = fmaxf(acc.z, 0.f); acc.w = fmaxf(acc.w, 0.f);
        *(float4*)&h_lds[s_l][i_l] = acc;
    }
    __syncthreads();

    // phase 2: out = h @ W2 + b2 ; 4 samples x 4 cols per thread
    int sg = t >> 6;
    int c4 = (t & 63) * 4;
    float4 bb = *(const float4*)(b2 + c4);
    float4 a0 = bb, a1 = bb, a2 = bb, a3 = bb;
    const int sO = sg * 4;

#pragma unroll 2
    for (int i4 = 0; i4 < 16; ++i4) {
        const float* wrow = W2 + i4 * 4 * 256 + c4;
        float4 w0 = *(const float4*)(wrow);
        float4 w1 = *(const float4*)(wrow + 256);
        float4 w2 = *(const float4*)(wrow + 512);
        float4 w3 = *(const float4*)(wrow + 768);
        float4 h0 = *(const float4*)&h_lds[sO + 0][i4 * 4];
        float4 h1 = *(const float4*)&h_lds[sO + 1][i4 * 4];
        float4 h2 = *(const float4*)&h_lds[sO + 2][i4 * 4];
        float4 h3 = *(const float4*)&h_lds[sO + 3][i4 * 4];

        a0.x += h0.x*w0.x + h0.y*w1.x + h0.z*w2.x + h0.w*w3.x;
        a0.y += h0.x*w0.y + h0.y*w1.y + h0.z*w2.y + h0.w*w3.y;
        a0.z += h0.x*w0.z + h0.y*w1.z + h0.z*w2.z + h0.w*w3.z;
        a0.w += h0.x*w0.w + h0.y*w1.w + h0.z*w2.w + h0.w*w3.w;

        a1.x += h1.x*w0.x + h1.y*w1.x + h1.z*w2.x + h1.w*w3.x;
        a1.y += h1.x*w0.y + h1.y*w1.y + h1.z*w2.y + h1.w*w3.y;
        a1.z += h1.x*w0.z + h1.y*w1.z + h1.z*w2.z + h1.w*w3.z;
        a1.w += h1.x*w0.w + h1.y*w1.w + h1.z*w2.w + h1.w*w3.w;

        a2.x += h2.x*w0.x + h2.y*w1.x + h2.z*w2.x + h2.w*w3.x;
        a2.y += h2.x*w0.y + h2.y*w1.y + h2.z*w2.y + h2.w*w3.y;
        a2.z += h2.x*w0.z + h2.y*w1.z + h2.z*w2.z + h2.w*w3.z;
        a2.w += h2.x*w0.w + h2.y*w1.w + h2.z*w2.w + h2.w*w3.w;

        a3.x += h3.x*w0.x + h3.y*w1.x + h3.z*w2.x + h3.w*w3.x;
        a3.y += h3.x*w0.y + h3.y*w1.y + h3.z*w2.y + h3.w*w3.y;
        a3.z += h3.x*w0.z + h3.y*w1.z + h3.z*w2.z + h3.w*w3.z;
        a3.w += h3.x*w0.w + h3.y*w1.w + h3.z*w2.w + h3.w*w3.w;
    }

    int srow = sbase + sO;
    if (srow + 0 < B) *(float4*)(out + (srow + 0) * 256 + c4) = a0;
    if (srow + 1 < B) *(float4*)(out + (srow + 1) * 256 + c4) = a1;
    if (srow + 2 < B) *(float4*)(out + (srow + 2) * 256 + c4) = a2;
    if (srow + 3 < B) *(float4*)(out + (srow + 3) * 256 + c4) = a3;
}

extern "C" void kernel_launch(void* const* d_in, const int* in_sizes, int n_in,
                              void* d_out, int out_size, void* d_ws, size_t ws_size,
                              hipStream_t stream) {
    const float* x  = (const float*)d_in[0];
    const float* qw = (const float*)d_in[1];
    const float* W1 = (const float*)d_in[2];
    const float* b1 = (const float*)d_in[3];
    const float* W2 = (const float*)d_in[4];
    const float* b2 = (const float*)d_in[5];
    float* out = (float*)d_out;
    float* zws = (float*)d_ws;          // needs B*8*4 = 256 KiB

    int B = in_sizes[0] / NQ;           // 8192

    qcircuit_z<<<(B + 15) / 16, 256, 0, stream>>>(x, qw, zws, B);   // 16 samples/block (4/wave)
    qmlp2<<<(B + 15) / 16, 256, 0, stream>>>(zws, W1, b1, W2, b2, out, B);
}

// Round 10
// 21.719 us; speedup vs baseline: 3.3868x; 1.1144x over previous
//
#include <hip/hip_runtime.h>

#define NQ 8
#define NLAYERS 3

typedef unsigned int uint2ev __attribute__((ext_vector_type(2)));

// ---- row-local xor exchange (16-lane rows), zero DS ops ----
template<int MASK>
__device__ __forceinline__ float xorlane(float v, int r) {
    if constexpr (MASK == 1) {
        return __int_as_float(__builtin_amdgcn_mov_dpp(__float_as_int(v), 0xB1, 0xF, 0xF, false)); // quad_perm [1,0,3,2]
    } else if constexpr (MASK == 2) {
        return __int_as_float(__builtin_amdgcn_mov_dpp(__float_as_int(v), 0x4E, 0xF, 0xF, false)); // quad_perm [2,3,0,1]
    } else if constexpr (MASK == 4) {
        float a = __int_as_float(__builtin_amdgcn_update_dpp(0, __float_as_int(v), 0x114, 0xF, 0xF, false)); // row_shr:4
        float b = __int_as_float(__builtin_amdgcn_update_dpp(0, __float_as_int(v), 0x104, 0xF, 0xF, false)); // row_shl:4
        return (r & 4) ? a : b;
    } else if constexpr (MASK == 8) {
        return __int_as_float(__builtin_amdgcn_mov_dpp(__float_as_int(v), 0x128, 0xF, 0xF, false)); // row_ror:8 == xor 8 in row16
    }
}

// ---- DPP-fused row16 sum; row total lands in lane r=15 of each row ----
template<int CTRL>
__device__ __forceinline__ float dpp_add_stage(float v) {
    int moved = __builtin_amdgcn_update_dpp(0, __float_as_int(v), CTRL, 0xF, 0xF, false);
    return v + __int_as_float(moved);
}
__device__ __forceinline__ float rowsum15(float v) {
    v = dpp_add_stage<0x111>(v);   // row_shr:1
    v = dpp_add_stage<0x112>(v);   // row_shr:2
    v = dpp_add_stage<0x114>(v);   // row_shr:4
    v = dpp_add_stage<0x118>(v);   // row_shr:8
    return v;                      // lane 15 of each 16-row has the row sum
}

__device__ __forceinline__ void ry_pair(float c, float s, float& a0, float& a1) {
    float n0 = c * a0 - s * a1;
    float n1 = s * a0 + c * a1;
    a0 = n0; a1 = n1;
}

__device__ __forceinline__ void rz_amp(float cp, float ssp, float& re, float& im) {
    float nr = re * cp - im * ssp;
    float ni = im * cp + re * ssp;
    re = nr; im = ni;
}

// qubits 0..3 -> j bits 0..3 (16 amps/lane); qubits 4..7 -> row-lane bits r0..r3
template<int Q>
__device__ __forceinline__ void ry16(float c, float s, float ar[16], float ai[16], int r) {
    if constexpr (Q < 4) {
        constexpr int M = 1 << Q;
#pragma unroll
        for (int j = 0; j < 16; ++j) if (!(j & M)) {
            ry_pair(c, s, ar[j], ar[j | M]);
            ry_pair(c, s, ai[j], ai[j | M]);
        }
    } else {
        constexpr int LM = 1 << (Q - 4);
        float sgn = (r & LM) ? s : -s;
#pragma unroll
        for (int j = 0; j < 16; ++j) {
            float pr = xorlane<LM>(ar[j], r);
            float pi = xorlane<LM>(ai[j], r);
            ar[j] = c * ar[j] + sgn * pr;
            ai[j] = c * ai[j] + sgn * pi;
        }
    }
}

template<int Q>
__device__ __forceinline__ void rz16(float cp, float sp, float ar[16], float ai[16], int r) {
    if constexpr (Q < 4) {
#pragma unroll
        for (int j = 0; j < 16; ++j) {
            float ssp = ((j >> Q) & 1) ? sp : -sp;
            rz_amp(cp, ssp, ar[j], ai[j]);
        }
    } else {
        float ssp = (r & (1 << (Q - 4))) ? sp : -sp;
#pragma unroll
        for (int j = 0; j < 16; ++j) rz_amp(cp, ssp, ar[j], ai[j]);
    }
}

#define SWAP2(a, b) { float _t = a; a = b; b = _t; }

// ring1: CNOT(0,1),(1,2),(2,3),(3,4),(4,5),(5,6),(6,7),(7,0)
__device__ __forceinline__ void ring16(float ar[16], float ai[16], int r) {
    // (0,1): j0=1 -> flip j1
    SWAP2(ar[1], ar[3]);  SWAP2(ai[1], ai[3]);
    SWAP2(ar[5], ar[7]);  SWAP2(ai[5], ai[7]);
    SWAP2(ar[9], ar[11]); SWAP2(ai[9], ai[11]);
    SWAP2(ar[13], ar[15]); SWAP2(ai[13], ai[15]);
    // (1,2): j1=1 -> flip j2
    SWAP2(ar[2], ar[6]);  SWAP2(ai[2], ai[6]);
    SWAP2(ar[3], ar[7]);  SWAP2(ai[3], ai[7]);
    SWAP2(ar[10], ar[14]); SWAP2(ai[10], ai[14]);
    SWAP2(ar[11], ar[15]); SWAP2(ai[11], ai[15]);
    // (2,3): j2=1 -> flip j3
    SWAP2(ar[4], ar[12]); SWAP2(ai[4], ai[12]);
    SWAP2(ar[5], ar[13]); SWAP2(ai[5], ai[13]);
    SWAP2(ar[6], ar[14]); SWAP2(ai[6], ai[14]);
    SWAP2(ar[7], ar[15]); SWAP2(ai[7], ai[15]);
    // (3,4): j3=1 -> flip r0
#pragma unroll
    for (int j = 8; j < 16; ++j) {
        ar[j] = xorlane<1>(ar[j], r);
        ai[j] = xorlane<1>(ai[j], r);
    }
    // (4,5): ctrl r0, tgt r1
    {
        bool hi = (r & 1) != 0;
#pragma unroll
        for (int j = 0; j < 16; ++j) {
            float pr = xorlane<2>(ar[j], r);
            float pi = xorlane<2>(ai[j], r);
            ar[j] = hi ? pr : ar[j];
            ai[j] = hi ? pi : ai[j];
        }
    }
    // (5,6): ctrl r1, tgt r2
    {
        bool hi = (r & 2) != 0;
#pragma unroll
        for (int j = 0; j < 16; ++j) {
            float pr = xorlane<4>(ar[j], r);
            float pi = xorlane<4>(ai[j], r);
            ar[j] = hi ? pr : ar[j];
            ai[j] = hi ? pi : ai[j];
        }
    }
    // (6,7): ctrl r2, tgt r3
    {
        bool hi = (r & 4) != 0;
#pragma unroll
        for (int j = 0; j < 16; ++j) {
            float pr = xorlane<8>(ar[j], r);
            float pi = xorlane<8>(ai[j], r);
            ar[j] = hi ? pr : ar[j];
            ai[j] = hi ? pi : ai[j];
        }
    }
    // (7,0): ctrl r3, tgt j0
    {
        bool hi = (r & 8) != 0;
#pragma unroll
        for (int j = 0; j < 16; j += 2) {
            float t0r = ar[j], t1r = ar[j + 1];
            ar[j]     = hi ? t1r : t0r;
            ar[j + 1] = hi ? t0r : t1r;
            float t0i = ai[j], t1i = ai[j + 1];
            ai[j]     = hi ? t1i : t0i;
            ai[j + 1] = hi ? t0i : t1i;
        }
    }
}

#define CMUL(rr, ri, xr, xi, yr, yi) { float _tr = (xr)*(yr) - (xi)*(yi); \
                                       float _ti = (xr)*(yi) + (xi)*(yr); \
                                       rr = _tr; ri = _ti; }

// ============ FUSED kernel: circuit (4 samples/wave) + MLP, 16 samples/block ============
__global__ __launch_bounds__(256) void qfused(
    const float* __restrict__ x,        // [B,8]
    const float* __restrict__ qw,       // [3,8,2]
    const float* __restrict__ W1,       // [8,64]
    const float* __restrict__ b1,       // [64]
    const float* __restrict__ W2,       // [64,256]
    const float* __restrict__ b2,       // [256]
    float* __restrict__ out,            // [B,256]
    int B)
{
    __shared__ float4 tab[NLAYERS * NQ];
    __shared__ float z_lds[16][8];
    __shared__ float h_lds[16][64];

    int tid = threadIdx.x;
    if (tid < NLAYERS * NQ) {
        float w0 = 0.5f * qw[tid * 2 + 0];
        float w1 = 0.5f * qw[tid * 2 + 1];
        if (tid < 8)
            tab[tid] = make_float4(w0, 0.f, __cosf(w1), __sinf(w1));
        else
            tab[tid] = make_float4(__cosf(w0), __sinf(w0), __cosf(w1), __sinf(w1));
    }
    __syncthreads();

    int lane = tid & 63;
    int wid  = tid >> 6;
    int g    = lane >> 4;               // sample group in wave
    int r    = lane & 15;               // row-lane bits r0..r3
    int sl   = wid * 4 + g;             // sample slot in block (0..15)
    int sbase = blockIdx.x * 16;
    int sample = sbase + sl;
    if (sample >= B) sample = B - 1;    // clamp: all threads must reach barriers

    // ---- per-lane encode of its own sample ----
    const float4* x4 = (const float4*)(x + sample * 8);
    float4 xa = x4[0], xb = x4[1];
    float xs[8] = {xa.x, xa.y, xa.z, xa.w, xb.x, xb.y, xb.z, xb.w};
    float xmin = xs[0], xmax = xs[0];
#pragma unroll
    for (int q = 1; q < 8; ++q) {
        xmin = fminf(xmin, xs[q]);
        xmax = fmaxf(xmax, xs[q]);
    }
    float inv_pi2 = 1.5707963267948966f / (xmax - xmin + 1e-8f);

    float cc[8], ss[8], cw[8], sw[8];
#pragma unroll
    for (int q = 0; q < 8; ++q) {
        float4 t0 = tab[q];
        float a = fmaf(xs[q] - xmin, inv_pi2, t0.x);
        cc[q] = __cosf(a);
        ss[q] = __sinf(a);
        cw[q] = t0.z;
        sw[q] = t0.w;
    }

    // f_q(b) = ((b? ss:cc)*cw, (b? +1:-1)*(b? ss:cc)*sw)
    int r0v = r & 1, r3v = (r >> 3) & 1;

    float X0r[2], X0i[2], X1r[2], X1i[2], X2r[2], X2i[2], X3r[2], X3i[2], X4r[2], X4i[2];
#pragma unroll
    for (int k = 0; k < 2; ++k) {
        { int b = k ^ r3v; float rr = b ? ss[0] : cc[0];
          X0r[k] = rr * cw[0]; X0i[k] = (b ? rr : -rr) * sw[0]; }
        { int b = k ^ r3v; float rr = b ? ss[1] : cc[1];
          X1r[k] = rr * cw[1]; X1i[k] = (b ? rr : -rr) * sw[1]; }
        { int b = k;        float rr = b ? ss[2] : cc[2];
          X2r[k] = rr * cw[2]; X2i[k] = (b ? rr : -rr) * sw[2]; }
        { int b = k;        float rr = b ? ss[3] : cc[3];
          X3r[k] = rr * cw[3]; X3i[k] = (b ? rr : -rr) * sw[3]; }
        { int b = k ^ r0v;  float rr = b ? ss[4] : cc[4];
          X4r[k] = rr * cw[4]; X4i[k] = (b ? rr : -rr) * sw[4]; }
    }

    // plane = f5(r0^r1) * f6(r1^r2) * f7(r2^r3)
    float plr, pli;
    {
        int b5 = (r ^ (r >> 1)) & 1;
        int b6 = ((r >> 1) ^ (r >> 2)) & 1;
        int b7 = ((r >> 2) ^ (r >> 3)) & 1;
        float r5 = b5 ? ss[5] : cc[5];
        float f5r = r5 * cw[5], f5i = (b5 ? r5 : -r5) * sw[5];
        float r6 = b6 ? ss[6] : cc[6];
        float f6r = r6 * cw[6], f6i = (b6 ? r6 : -r6) * sw[6];
        float r7 = b7 ? ss[7] : cc[7];
        float f7r = r7 * cw[7], f7i = (b7 ? r7 : -r7) * sw[7];
        CMUL(plr, pli, f5r, f5i, f6r, f6i);
        CMUL(plr, pli, plr, pli, f7r, f7i);
    }

    // PP[j0][j1] = plane * X0[j0] * X1[j0^j1]
    float PPr[2][2], PPi[2][2];
    {
        float t0r, t0i, t1r, t1i;
        CMUL(t0r, t0i, plr, pli, X0r[0], X0i[0]);
        CMUL(t1r, t1i, plr, pli, X0r[1], X0i[1]);
        CMUL(PPr[0][0], PPi[0][0], t0r, t0i, X1r[0], X1i[0]);
        CMUL(PPr[0][1], PPi[0][1], t0r, t0i, X1r[1], X1i[1]);
        CMUL(PPr[1][0], PPi[1][0], t1r, t1i, X1r[1], X1i[1]);
        CMUL(PPr[1][1], PPi[1][1], t1r, t1i, X1r[0], X1i[0]);
    }
    // Q34[j2][j3] = X3[j2^j3] * X4[j3]
    float Qr[2][2], Qi[2][2];
    CMUL(Qr[0][0], Qi[0][0], X3r[0], X3i[0], X4r[0], X4i[0]);
    CMUL(Qr[0][1], Qi[0][1], X3r[1], X3i[1], X4r[1], X4i[1]);
    CMUL(Qr[1][0], Qi[1][0], X3r[1], X3i[1], X4r[0], X4i[0]);
    CMUL(Qr[1][1], Qi[1][1], X3r[0], X3i[0], X4r[1], X4i[1]);
    // R[j1][j2][j3] = X2[j1^j2] * Q34[j2][j3]
    float Rr[2][2][2], Ri[2][2][2];
#pragma unroll
    for (int j1 = 0; j1 < 2; ++j1)
#pragma unroll
        for (int j2 = 0; j2 < 2; ++j2)
#pragma unroll
            for (int j3 = 0; j3 < 2; ++j3) {
                int k = j1 ^ j2;
                CMUL(Rr[j1][j2][j3], Ri[j1][j2][j3], X2r[k], X2i[k], Qr[j2][j3], Qi[j2][j3]);
            }

    float ar[16], ai[16];
#pragma unroll
    for (int j3 = 0; j3 < 2; ++j3)
#pragma unroll
        for (int j2 = 0; j2 < 2; ++j2)
#pragma unroll
            for (int j1 = 0; j1 < 2; ++j1)
#pragma unroll
                for (int j0 = 0; j0 < 2; ++j0) {
                    int j = j0 + 2 * j1 + 4 * j2 + 8 * j3;
                    CMUL(ar[j], ai[j], PPr[j0][j1], PPi[j0][j1], Rr[j1][j2][j3], Ri[j1][j2][j3]);
                }

    // ---- layer 1: RY + RZ all qubits ----
    {
        float4 t;
        t = tab[8];  ry16<0>(t.x, t.y, ar, ai, r); rz16<0>(t.z, t.w, ar, ai, r);
        t = tab[9];  ry16<1>(t.x, t.y, ar, ai, r); rz16<1>(t.z, t.w, ar, ai, r);
        t = tab[10]; ry16<2>(t.x, t.y, ar, ai, r); rz16<2>(t.z, t.w, ar, ai, r);
        t = tab[11]; ry16<3>(t.x, t.y, ar, ai, r); rz16<3>(t.z, t.w, ar, ai, r);
        t = tab[12]; ry16<4>(t.x, t.y, ar, ai, r); rz16<4>(t.z, t.w, ar, ai, r);
        t = tab[13]; ry16<5>(t.x, t.y, ar, ai, r); rz16<5>(t.z, t.w, ar, ai, r);
        t = tab[14]; ry16<6>(t.x, t.y, ar, ai, r); rz16<6>(t.z, t.w, ar, ai, r);
        t = tab[15]; ry16<7>(t.x, t.y, ar, ai, r); rz16<7>(t.z, t.w, ar, ai, r);
    }
    ring16(ar, ai, r);
    {
        float4 t;
        t = tab[16]; ry16<0>(t.x, t.y, ar, ai, r);
        t = tab[17]; ry16<1>(t.x, t.y, ar, ai, r);
        t = tab[18]; ry16<2>(t.x, t.y, ar, ai, r);
        t = tab[19]; ry16<3>(t.x, t.y, ar, ai, r);
        t = tab[20]; ry16<4>(t.x, t.y, ar, ai, r);
        t = tab[21]; ry16<5>(t.x, t.y, ar, ai, r);
        t = tab[22]; ry16<6>(t.x, t.y, ar, ai, r);
        t = tab[23]; ry16<7>(t.x, t.y, ar, ai, r);
    }

    // ---- measurement through folded ring2 ----
    float P[16];
#pragma unroll
    for (int j = 0; j < 16; ++j) P[j] = ar[j] * ar[j] + ai[j] * ai[j];

    float Sp[8], Dp[8];
#pragma unroll
    for (int k = 0; k < 8; ++k) {
        Sp[k] = P[2 * k] + P[2 * k + 1];
        Dp[k] = P[2 * k] - P[2 * k + 1];
    }
    float U0 = ((Sp[0] - Sp[1]) - (Sp[2] - Sp[3])) - ((Sp[4] - Sp[5]) - (Sp[6] - Sp[7]));
    float U3 = ((Dp[0] - Dp[1]) - (Dp[2] - Dp[3])) - ((Dp[4] - Dp[5]) - (Dp[6] - Dp[7]));
    float U1 = (Dp[0] - Dp[1]) + (Dp[2] - Dp[3]) + (Dp[4] - Dp[5]) + (Dp[6] - Dp[7]);
    float U2 = ((Dp[0] - Dp[1]) - (Dp[2] - Dp[3])) + ((Dp[4] - Dp[5]) - (Dp[6] - Dp[7]));

    int p1 = r & 1;
    int p2 = (r ^ (r >> 1)) & 1;
    int p3 = (r ^ (r >> 1) ^ (r >> 2)) & 1;
    int p4 = (r ^ (r >> 1) ^ (r >> 2) ^ (r >> 3)) & 1;

    float z0 = rowsum15(p4 ? -U0 : U0);
    float z1 = rowsum15(U1);
    float z2 = rowsum15(U2);
    float z3 = rowsum15(U3);
    float z4 = rowsum15(p1 ? -U3 : U3);
    float z5 = rowsum15(p2 ? -U3 : U3);
    float z6 = rowsum15(p3 ? -U3 : U3);
    float z7 = rowsum15(p4 ? -U3 : U3);

    if (r == 15) {
        *(float4*)&z_lds[sl][0] = make_float4(z0, z1, z2, z3);
        *(float4*)&z_lds[sl][4] = make_float4(z4, z5, z6, z7);
    }
    __syncthreads();

    // ---- MLP phase 1: h[16][64] tile ----
    {
        int s_l = tid >> 4;
        int i_l = (tid & 15) * 4;
        float4 za = *(const float4*)&z_lds[s_l][0];
        float4 zb = *(const float4*)&z_lds[s_l][4];
        float zq[8] = {za.x, za.y, za.z, za.w, zb.x, zb.y, zb.z, zb.w};
        float4 acc = *(const float4*)(b1 + i_l);
#pragma unroll
        for (int q = 0; q < 8; ++q) {
            float4 w = *(const float4*)(W1 + q * 64 + i_l);
            acc.x += zq[q] * w.x; acc.y += zq[q] * w.y;
            acc.z += zq[q] * w.z; acc.w += zq[q] * w.w;
        }
        acc.x = fmaxf(acc.x, 0.f); acc.y = fmaxf(acc.y, 0.f);
        acc.z = fmaxf(acc.z, 0.f); acc.w = fmaxf(acc.w, 0.f);
        *(float4*)&h_lds[s_l][i_l] = acc;
    }
    __syncthreads();

    // ---- MLP phase 2: out = h @ W2 + b2 ; 4 samples x 4 cols per thread ----
    int sg = tid >> 6;
    int c4 = (tid & 63) * 4;
    float4 bb = *(const float4*)(b2 + c4);
    float4 a0 = bb, a1 = bb, a2 = bb, a3 = bb;
    const int sO = sg * 4;

#pragma unroll 2
    for (int i4 = 0; i4 < 16; ++i4) {
        const float* wrow = W2 + i4 * 4 * 256 + c4;
        float4 w0 = *(const float4*)(wrow);
        float4 w1 = *(const float4*)(wrow + 256);
        float4 w2 = *(const float4*)(wrow + 512);
        float4 w3 = *(const float4*)(wrow + 768);
        float4 h0 = *(const float4*)&h_lds[sO + 0][i4 * 4];
        float4 h1 = *(const float4*)&h_lds[sO + 1][i4 * 4];
        float4 h2 = *(const float4*)&h_lds[sO + 2][i4 * 4];
        float4 h3 = *(const float4*)&h_lds[sO + 3][i4 * 4];

        a0.x += h0.x*w0.x + h0.y*w1.x + h0.z*w2.x + h0.w*w3.x;
        a0.y += h0.x*w0.y + h0.y*w1.y + h0.z*w2.y + h0.w*w3.y;
        a0.z += h0.x*w0.z + h0.y*w1.z + h0.z*w2.z + h0.w*w3.z;
        a0.w += h0.x*w0.w + h0.y*w1.w + h0.z*w2.w + h0.w*w3.w;

        a1.x += h1.x*w0.x + h1.y*w1.x + h1.z*w2.x + h1.w*w3.x;
        a1.y += h1.x*w0.y + h1.y*w1.y + h1.z*w2.y + h1.w*w3.y;
        a1.z += h1.x*w0.z + h1.y*w1.z + h1.z*w2.z + h1.w*w3.z;
        a1.w += h1.x*w0.w + h1.y*w1.w + h1.z*w2.w + h1.w*w3.w;

        a2.x += h2.x*w0.x + h2.y*w1.x + h2.z*w2.x + h2.w*w3.x;
        a2.y += h2.x*w0.y + h2.y*w1.y + h2.z*w2.y + h2.w*w3.y;
        a2.z += h2.x*w0.z + h2.y*w1.z + h2.z*w2.z + h2.w*w3.z;
        a2.w += h2.x*w0.w + h2.y*w1.w + h2.z*w2.w + h2.w*w3.w;

        a3.x += h3.x*w0.x + h3.y*w1.x + h3.z*w2.x + h3.w*w3.x;
        a3.y += h3.x*w0.y + h3.y*w1.y + h3.z*w2.y + h3.w*w3.y;
        a3.z += h3.x*w0.z + h3.y*w1.z + h3.z*w2.z + h3.w*w3.z;
        a3.w += h3.x*w0.w + h3.y*w1.w + h3.z*w2.w + h3.w*w3.w;
    }

    int srow = sbase + sO;
    if (srow + 0 < B) *(float4*)(out + (srow + 0) * 256 + c4) = a0;
    if (srow + 1 < B) *(float4*)(out + (srow + 1) * 256 + c4) = a1;
    if (srow + 2 < B) *(float4*)(out + (srow + 2) * 256 + c4) = a2;
    if (srow + 3 < B) *(float4*)(out + (srow + 3) * 256 + c4) = a3;
}

extern "C" void kernel_launch(void* const* d_in, const int* in_sizes, int n_in,
                              void* d_out, int out_size, void* d_ws, size_t ws_size,
                              hipStream_t stream) {
    const float* x  = (const float*)d_in[0];
    const float* qw = (const float*)d_in[1];
    const float* W1 = (const float*)d_in[2];
    const float* b1 = (const float*)d_in[3];
    const float* W2 = (const float*)d_in[4];
    const float* b2 = (const float*)d_in[5];
    float* out = (float*)d_out;

    int B = in_sizes[0] / NQ;           // 8192

    qfused<<<(B + 15) / 16, 256, 0, stream>>>(x, qw, W1, b1, W2, b2, out, B);
}